// Round 8
// baseline (275.251 us; speedup 1.0000x reference)
//
#include <hip/hip_runtime.h>
#include <math.h>

#define BB 8
#define CCH 256
#define QQ 4
#define NN 1600          // H*W
#define BQN 32           // B*Q
#define SP 51200         // BQN*NN
#define EPSF 1e-5f

typedef __attribute__((ext_vector_type(8))) short bf16x8;  // 8 bf16 (4 VGPRs)
typedef __attribute__((ext_vector_type(4))) float f32x4;

static __device__ inline ushort f2bf(float f) {
  union { float f; unsigned u; } v; v.f = f;
  return (ushort)((v.u + 0x7fffu + ((v.u >> 16) & 1u)) >> 16);  // RNE
}
static __device__ inline float bf2f(ushort u) {
  union { unsigned u; float f; } v; v.u = ((unsigned)u) << 16;
  return v.f;
}
// async 16B global->LDS (lane-linear dest)
static __device__ inline void gld16(const ushort* g, ushort* l) {
  __builtin_amdgcn_global_load_lds(
      (const __attribute__((address_space(1))) unsigned int*)g,
      (__attribute__((address_space(3))) unsigned int*)l, 16, 0, 0);
}

// ---------------- merged: fake-quant weights (blk<1025) + prep x (blk>=1025) ----------------
__global__ __launch_bounds__(256)
void qp_kernel(const float* __restrict__ Wq, const float* __restrict__ Wk,
               const float* __restrict__ Wv, const float* __restrict__ Wp,
               const float* __restrict__ gamma, const float* __restrict__ x,
               ushort* __restrict__ wq, ushort* __restrict__ wk,
               ushort* __restrict__ wvT, ushort* __restrict__ wp,
               ushort* __restrict__ wqT, ushort* __restrict__ wkT,
               ushort* __restrict__ wpT, float* __restrict__ gq,
               ushort* __restrict__ xb, ushort* __restrict__ xT,
               float* __restrict__ rpart) {
  __shared__ float red[256];
  __shared__ ushort lT[64 * 66];
  int blk = blockIdx.x;
  int tid = threadIdx.x;
  if (blk < 1024) {
    int mat = blk >> 8;
    int row = blk & 255;
    const float* W = (mat == 0) ? Wq : (mat == 1) ? Wk : (mat == 2) ? Wv : Wp;
    float w = W[row * 256 + tid];
    red[tid] = fabsf(w);
    __syncthreads();
    for (int s = 128; s > 0; s >>= 1) {
      if (tid < s) red[tid] = fmaxf(red[tid], red[tid + s]);
      __syncthreads();
    }
    float s = red[0] / 127.0f + 1e-8f;
    float q = fminf(fmaxf(rintf(w / s), -127.0f), 127.0f) * s;
    ushort qb = f2bf(q);
    if (mat == 0)      { wq[row * 256 + tid] = qb; wqT[tid * 256 + row] = qb; }
    else if (mat == 1) { wk[row * 256 + tid] = qb; wkT[tid * 256 + row] = qb; }
    else if (mat == 2) { wvT[tid * 256 + row] = qb; }   // wvT[i][d]=Wv[d][i]
    else               { wp[row * 256 + tid] = qb; wpT[tid * 256 + row] = qb; }
    return;
  }
  if (blk == 1024) {
    float g = gamma[tid];
    red[tid] = fabsf(g);
    __syncthreads();
    for (int s = 128; s > 0; s >>= 1) {
      if (tid < s) red[tid] = fmaxf(red[tid], red[tid + s]);
      __syncthreads();
    }
    float s = red[0] / 127.0f + 1e-8f;
    gq[tid] = fminf(fmaxf(rintf(g / s), -127.0f), 127.0f) * s;
    return;
  }
  // ---- prep ----
  int p = blk - 1025;            // 0..3199
  int sx = p % 25;
  int rem = p / 25;              // 0..127
  int cy = rem & 3, bqi = rem >> 2;
  int b = bqi >> 2, q = bqi & 3;
  int s0 = sx * 64, c0 = cy * 64;
  int c = tid >> 2, nch = (tid & 3) * 16;
  const float* xp = x + ((size_t)(b * CCH + c0 + c) * QQ + q) * NN + s0 + nch;
  union { ushort u[16]; int4 v[2]; } nb;
  float s = 0.f;
#pragma unroll
  for (int j = 0; j < 4; j++) {
    float4 f = ((const float4*)xp)[j];
    ushort b0 = f2bf(f.x), b1 = f2bf(f.y), b2 = f2bf(f.z), b3 = f2bf(f.w);
    s += bf2f(b0) + bf2f(b1) + bf2f(b2) + bf2f(b3);
    nb.u[j * 4 + 0] = b0;
    nb.u[j * 4 + 1] = b1;
    nb.u[j * 4 + 2] = b2;
    nb.u[j * 4 + 3] = b3;
    lT[c * 66 + nch + j * 4 + 0] = b0;
    lT[c * 66 + nch + j * 4 + 1] = b1;
    lT[c * 66 + nch + j * 4 + 2] = b2;
    lT[c * 66 + nch + j * 4 + 3] = b3;
  }
  ushort* xbp = xb + (size_t)bqi * (CCH * NN) + (size_t)(c0 + c) * NN + s0 + nch;
  *(int4*)xbp = nb.v[0];
  *((int4*)xbp + 1) = nb.v[1];
  s += __shfl_down(s, 2);
  s += __shfl_down(s, 1);
  if ((tid & 3) == 0) rpart[((size_t)bqi * 25 + sx) * 256 + c0 + c] = s;
  __syncthreads();
  int n = tid >> 2, cch = (tid & 3) * 16;
  union { ushort u[16]; int4 v[2]; } o;
#pragma unroll
  for (int i = 0; i < 16; i++) o.u[i] = lT[(cch + i) * 66 + n];
  ushort* dst = xT + (size_t)(bqi * NN + s0 + n) * CCH + c0 + cch;
  *(int4*)dst = o.v[0];
  *((int4*)dst + 1) = o.v[1];
}

// ---------------- Gram (symmetric, LDS dbuf) + uv slot, XCD z-grouped ----------------
__global__ __launch_bounds__(256)
void gram_uv_kernel(const ushort* __restrict__ xb, ushort* __restrict__ Gh,
                    ushort* __restrict__ Gl,
                    const ushort* __restrict__ wqT, const ushort* __restrict__ wkT,
                    const float* __restrict__ rpart, float* __restrict__ r,
                    float* __restrict__ u, float* __restrict__ vv) {
  __shared__ __align__(16) char smem[16384];
  __shared__ float rs[256];
  // 352 blocks = 8 XCD slots x 44; XCD k owns z in [4k, 4k+4)
  int lin = blockIdx.x + 11 * blockIdx.y;
  int k8 = lin & 7, j = lin >> 3;          // j in [0,44)
  int z = 4 * k8 + j / 11, t = j % 11;
  int tid = threadIdx.x;
  if (t == 10) {
    float rv = 0.f;
#pragma unroll
    for (int k = 0; k < 25; k++) rv += rpart[((size_t)z * 25 + k) * 256 + tid];
    rs[tid] = rv;
    r[z * 256 + tid] = rv;
    __syncthreads();
    float su = 0.f, sv = 0.f;
    for (int i = 0; i < 256; i++) {
      float rr = rs[i];
      su += bf2f(wqT[i * 256 + tid]) * rr;
      sv += bf2f(wkT[i * 256 + tid]) * rr;
    }
    u[z * 256 + tid] = su;
    vv[z * 256 + tid] = sv;
    return;
  }
  int ty = (t >= 4) + (t >= 7) + (t >= 9);
  int base = ty * 4 - (ty * (ty - 1)) / 2;
  int tx = ty + (t - base);
  int mBase = ty * 64, nBase = tx * 64;
  bool offd = (tx != ty);
  int wave = tid >> 6, lane = tid & 63;
  int wm = wave >> 1, wn = wave & 1;
  int col = lane & 15, quad = lane >> 4;
  const ushort* X = xb + (size_t)z * (CCH * NN);
  const ushort* gA = X + (size_t)(mBase + (tid >> 2)) * NN + (tid & 3) * 8;
  const ushort* gB = X + (size_t)(nBase + (tid >> 2)) * NN + (tid & 3) * 8;
  f32x4 acc[2][2];
#pragma unroll
  for (int i = 0; i < 2; i++)
#pragma unroll
    for (int j2 = 0; j2 < 2; j2++) acc[i][j2] = (f32x4){0.f, 0.f, 0.f, 0.f};

  const int nIter = NN / 32;   // 50
  gld16(gA, (ushort*)smem + tid * 8);
  gld16(gB, (ushort*)(smem + 4096) + tid * 8);
  for (int it = 0; it < nIter; ++it) {
    int cur = it & 1;
    __syncthreads();
    if (it + 1 < nIter) {
      int kt = (it + 1) << 5;
      char* bb = smem + (cur ^ 1) * 8192;
      gld16(gA + kt, (ushort*)bb + tid * 8);
      gld16(gB + kt, (ushort*)(bb + 4096) + tid * 8);
    }
    const ushort* lA = (const ushort*)(smem + cur * 8192);
    const ushort* lB = lA + 2048;
    bf16x8 af[2], bfr[2];
#pragma unroll
    for (int i = 0; i < 2; i++)
      af[i] = *(const bf16x8*)&lA[(wm * 32 + i * 16 + col) * 32 + quad * 8];
#pragma unroll
    for (int j2 = 0; j2 < 2; j2++)
      bfr[j2] = *(const bf16x8*)&lB[(wn * 32 + j2 * 16 + col) * 32 + quad * 8];
#pragma unroll
    for (int i = 0; i < 2; i++)
#pragma unroll
      for (int j2 = 0; j2 < 2; j2++)
        acc[i][j2] = __builtin_amdgcn_mfma_f32_16x16x32_bf16(af[i], bfr[j2], acc[i][j2], 0, 0, 0);
  }
  __syncthreads();
  float* lCw = (float*)smem + wave * 576;
#pragma unroll
  for (int i = 0; i < 2; i++) {
#pragma unroll
    for (int j2 = 0; j2 < 2; j2++)
#pragma unroll
      for (int rg = 0; rg < 4; rg++)
        lCw[(quad * 4 + rg) * 36 + j2 * 16 + col] = acc[i][j2][rg];
    int mrow0 = mBase + wm * 32 + i * 16;
    int nW = nBase + wn * 32;
    int rr = lane >> 2, cc = (lane & 3) * 8;
    union { ushort u[8]; int4 v; } oh, ol;
#pragma unroll
    for (int t8 = 0; t8 < 8; t8++) {
      float vfl = lCw[rr * 36 + cc + t8];
      ushort hh = f2bf(vfl);
      oh.u[t8] = hh;
      ol.u[t8] = f2bf(vfl - bf2f(hh));
    }
    size_t off = (size_t)z * 65536 + (size_t)(mrow0 + rr) * 256 + nW + cc;
    *(int4*)(Gh + off) = oh.v;
    *(int4*)(Gl + off) = ol.v;
    if (offd) {
      int nn = lane >> 1, mh = (lane & 1) * 8;
      union { ushort u[8]; int4 v; } th, tl;
#pragma unroll
      for (int t8 = 0; t8 < 8; t8++) {
        float vfl = lCw[(mh + t8) * 36 + nn];
        ushort hh = f2bf(vfl);
        th.u[t8] = hh;
        tl.u[t8] = f2bf(vfl - bf2f(hh));
      }
      size_t offT = (size_t)z * 65536 + (size_t)(nW + nn) * 256 + mrow0 + mh;
      *(int4*)(Gh + offT) = th.v;
      *(int4*)(Gl + offT) = tl.v;
    }
  }
}

// ---------------- fused S-path (R2/R5 body), XCD z-grouped ----------------
__global__ __launch_bounds__(256)
void spk_kernel(const ushort* __restrict__ wq, const ushort* __restrict__ Gh,
                const ushort* __restrict__ Gl, const ushort* __restrict__ wk,
                const float* __restrict__ ug, const float* __restrict__ vg,
                const float* __restrict__ bqv, const float* __restrict__ bkv,
                const float* __restrict__ bvv,
                ushort* __restrict__ P, float* __restrict__ pb) {
  // region0: staging dbuf 2 x 34816 B  (A 2048 | Bh 16384 @+2048 | Bl 16384 @+18432)
  // region1 @69632: M1h 32x264 (16896B) + M1l (16896B); reused as Sb 32x260 f32
  __shared__ __align__(16) char smem[103424];
  int lin = blockIdx.x + 8 * blockIdx.y;
  int k8 = lin & 7, j9 = lin >> 3;         // j9 in [0,32)
  int z = 4 * k8 + (j9 >> 3), mBase = (j9 & 7) * 32;
  int tid = threadIdx.x, wave = tid >> 6, lane = tid & 63;
  int col = lane & 15, quad = lane >> 4;
  int rA = tid >> 2, sub = (tid & 3) * 8;
  const ushort* Ghz = Gh + (size_t)z * 65536;
  const ushort* Glz = Gl + (size_t)z * 65536;
  ushort* M1h_l = (ushort*)(smem + 69632);
  ushort* M1l_l = M1h_l + 8448;

  // ---- stage 1: M1 strip = wq[mBase..+32] * (Gh+Gl)^T ----
  f32x4 acc[2][4];
#pragma unroll
  for (int i = 0; i < 2; i++)
#pragma unroll
    for (int j = 0; j < 4; j++) acc[i][j] = (f32x4){0.f, 0.f, 0.f, 0.f};

  auto s1_load = [&](int buf, int kt) {
    ushort* L = (ushort*)(smem + buf * 34816);
    if (tid < 128)
      gld16(wq + (size_t)(mBase + rA) * 256 + kt + sub, L + tid * 8);
    ushort* Lh = L + 1024;
    ushort* Ll = L + 9216;
#pragma unroll
    for (int q = 0; q < 4; q++) {
      int n = q * 64 + rA;
      gld16(Ghz + (size_t)n * 256 + kt + sub, Lh + (q * 256 + tid) * 8);
      gld16(Glz + (size_t)n * 256 + kt + sub, Ll + (q * 256 + tid) * 8);
    }
  };
  s1_load(0, 0);
  for (int it = 0; it < 8; ++it) {
    int cur = it & 1;
    __syncthreads();
    if (it + 1 < 8) s1_load(cur ^ 1, (it + 1) * 32);
    const ushort* L = (const ushort*)(smem + cur * 34816);
    const ushort* lA = L;
    const ushort* lBh = L + 1024;
    const ushort* lBl = L + 9216;
    bf16x8 af[2], bh[4], bl[4];
#pragma unroll
    for (int i = 0; i < 2; i++)
      af[i] = *(const bf16x8*)&lA[(i * 16 + col) * 32 + quad * 8];
#pragma unroll
    for (int j = 0; j < 4; j++) {
      bh[j] = *(const bf16x8*)&lBh[(wave * 64 + j * 16 + col) * 32 + quad * 8];
      bl[j] = *(const bf16x8*)&lBl[(wave * 64 + j * 16 + col) * 32 + quad * 8];
    }
#pragma unroll
    for (int i = 0; i < 2; i++)
#pragma unroll
      for (int j = 0; j < 4; j++) {
        acc[i][j] = __builtin_amdgcn_mfma_f32_16x16x32_bf16(af[i], bh[j], acc[i][j], 0, 0, 0);
        acc[i][j] = __builtin_amdgcn_mfma_f32_16x16x32_bf16(af[i], bl[j], acc[i][j], 0, 0, 0);
      }
  }
  // split M1 to bf16 hi/lo in LDS
#pragma unroll
  for (int i = 0; i < 2; i++)
#pragma unroll
    for (int j = 0; j < 4; j++)
#pragma unroll
      for (int rg = 0; rg < 4; rg++) {
        int ml = i * 16 + quad * 4 + rg;
        int cg = wave * 64 + j * 16 + col;
        float vfl = acc[i][j][rg];
        ushort hh = f2bf(vfl);
        M1h_l[ml * 264 + cg] = hh;
        M1l_l[ml * 264 + cg] = f2bf(vfl - bf2f(hh));
      }

  // ---- stage 2: S strip = (M1h + M1l) * wk^T ----
  f32x4 acc2[2][4];
#pragma unroll
  for (int i = 0; i < 2; i++)
#pragma unroll
    for (int j = 0; j < 4; j++) acc2[i][j] = (f32x4){0.f, 0.f, 0.f, 0.f};
  auto s2_load = [&](int buf, int kt) {
    ushort* L = (ushort*)(smem + buf * 34816);
#pragma unroll
    for (int q = 0; q < 4; q++)
      gld16(wk + (size_t)(q * 64 + rA) * 256 + kt + sub, L + (q * 256 + tid) * 8);
  };
  s2_load(0, 0);
  for (int it = 0; it < 8; ++it) {
    int cur = it & 1;
    __syncthreads();
    if (it + 1 < 8) s2_load(cur ^ 1, (it + 1) * 32);
    const ushort* lB = (const ushort*)(smem + cur * 34816);
    int kt = it * 32;
    bf16x8 ah[2], al[2], bfr[4];
#pragma unroll
    for (int i = 0; i < 2; i++) {
      ah[i] = *(const bf16x8*)&M1h_l[(i * 16 + col) * 264 + kt + quad * 8];
      al[i] = *(const bf16x8*)&M1l_l[(i * 16 + col) * 264 + kt + quad * 8];
    }
#pragma unroll
    for (int j = 0; j < 4; j++)
      bfr[j] = *(const bf16x8*)&lB[(wave * 64 + j * 16 + col) * 32 + quad * 8];
#pragma unroll
    for (int i = 0; i < 2; i++)
#pragma unroll
      for (int j = 0; j < 4; j++) {
        acc2[i][j] = __builtin_amdgcn_mfma_f32_16x16x32_bf16(ah[i], bfr[j], acc2[i][j], 0, 0, 0);
        acc2[i][j] = __builtin_amdgcn_mfma_f32_16x16x32_bf16(al[i], bfr[j], acc2[i][j], 0, 0, 0);
      }
  }
  __syncthreads();   // all waves done reading M1 LDS before overwrite with Sb

  // ---- bias + store S strip to LDS ----
  float* Sb = (float*)(smem + 69632);   // 32 x 260 f32
  float bkc[4], vvc[4];
#pragma unroll
  for (int j = 0; j < 4; j++) {
    int cg = wave * 64 + j * 16 + col;
    bkc[j] = bkv[cg];
    vvc[j] = vg[z * 256 + cg];
  }
#pragma unroll
  for (int i = 0; i < 2; i++)
#pragma unroll
    for (int rg = 0; rg < 4; rg++) {
      int ml = i * 16 + quad * 4 + rg;
      int rglob = mBase + ml;
      float uu = ug[z * 256 + rglob];
      float bqc = bqv[rglob];
#pragma unroll
      for (int j = 0; j < 4; j++)
        Sb[ml * 260 + wave * 64 + j * 16 + col] =
            0.125f * (acc2[i][j][rg] + uu * bkc[j] + bqc * vvc[j] + 1600.0f * bqc * bkc[j]);
    }
  __syncthreads();

  // ---- wave-parallel softmax: 8 rows per wave ----
  float4 bv4 = *(const float4*)(bvv + lane * 4);
#pragma unroll
  for (int rr8 = 0; rr8 < 8; ++rr8) {
    int rloc = wave * 8 + rr8;
    f32x4 sv = *(const f32x4*)&Sb[rloc * 260 + lane * 4];
    float x0 = sv[0], x1 = sv[1], x2 = sv[2], x3 = sv[3];
    float m = fmaxf(fmaxf(x0, x1), fmaxf(x2, x3));
#pragma unroll
    for (int s = 32; s > 0; s >>= 1) m = fmaxf(m, __shfl_xor(m, s));
    float e0 = expf(x0 - m), e1 = expf(x1 - m), e2 = expf(x2 - m), e3 = expf(x3 - m);
    float t = e0 + e1 + e2 + e3;
#pragma unroll
    for (int s = 32; s > 0; s >>= 1) t += __shfl_xor(t, s);
    float is = 1.0f / t;
    float p0 = e0 * is, p1 = e1 * is, p2 = e2 * is, p3 = e3 * is;
    union { ushort u[4]; uint2 v; } o;
    o.u[0] = f2bf(p0); o.u[1] = f2bf(p1); o.u[2] = f2bf(p2); o.u[3] = f2bf(p3);
    *(uint2*)(P + (size_t)z * 65536 + (size_t)(mBase + rloc) * 256 + lane * 4) = o.v;
    float d = p0 * bv4.x + p1 * bv4.y + p2 * bv4.z + p3 * bv4.w;
#pragma unroll
    for (int s = 32; s > 0; s >>= 1) d += __shfl_xor(d, s);
    if (lane == 0) pb[z * 256 + mBase + rloc] = d;
  }
}

// ---------------- fused T-path (R2/R5 body), XCD z-grouped ----------------
__global__ __launch_bounds__(256)
void pt_kernel(const ushort* __restrict__ P, const ushort* __restrict__ wvT,
               const ushort* __restrict__ wp,
               ushort* __restrict__ Tm, ushort* __restrict__ TmT,
               float* __restrict__ m_acc, float* __restrict__ v_acc) {
  // region0: staging dbuf 2 x 18432 B (big tile 16384 | small tile 2048 @+16384)
  // region1 @36864: N1buf 32x264 bf16 (16896B)
  __shared__ __align__(16) char smem[53760];
  int lin = blockIdx.x + 8 * blockIdx.y;
  int k8 = lin & 7, j9 = lin >> 3;
  int z = 4 * k8 + (j9 >> 3), cs = (j9 & 7) * 32;
  int tid = threadIdx.x, wave = tid >> 6, lane = tid & 63;
  int col = lane & 15, quad = lane >> 4;
  int rA = tid >> 2, sub = (tid & 3) * 8;
  if (lin == 0) {    // zero stats accumulators (read only after this kernel completes)
    m_acc[tid] = 0.f;
    v_acc[tid] = 0.f;
  }
  const ushort* Pz = P + (size_t)z * 65536;
  ushort* N1b = (ushort*)(smem + 36864);

  // ---- stage 3: N1[e, cs..+32] = P * Wv(:,cs..+32) ----
  f32x4 acc[4][2];
#pragma unroll
  for (int i = 0; i < 4; i++)
#pragma unroll
    for (int j = 0; j < 2; j++) acc[i][j] = (f32x4){0.f, 0.f, 0.f, 0.f};
  auto s3_load = [&](int buf, int kt) {
    ushort* L = (ushort*)(smem + buf * 18432);
#pragma unroll
    for (int q = 0; q < 4; q++)
      gld16(Pz + (size_t)(q * 64 + rA) * 256 + kt + sub, L + (q * 256 + tid) * 8);
    if (tid < 128)
      gld16(wvT + (size_t)(cs + rA) * 256 + kt + sub, L + 8192 + tid * 8);
  };
  s3_load(0, 0);
  for (int it = 0; it < 8; ++it) {
    int cur = it & 1;
    __syncthreads();
    if (it + 1 < 8) s3_load(cur ^ 1, (it + 1) * 32);
    const ushort* lP = (const ushort*)(smem + cur * 18432);
    const ushort* lV = lP + 8192;
    bf16x8 af[4], bfr[2];
#pragma unroll
    for (int i = 0; i < 4; i++)
      af[i] = *(const bf16x8*)&lP[(wave * 64 + i * 16 + col) * 32 + quad * 8];
#pragma unroll
    for (int j = 0; j < 2; j++)
      bfr[j] = *(const bf16x8*)&lV[(j * 16 + col) * 32 + quad * 8];
#pragma unroll
    for (int i = 0; i < 4; i++)
#pragma unroll
      for (int j = 0; j < 2; j++)
        acc[i][j] = __builtin_amdgcn_mfma_f32_16x16x32_bf16(af[i], bfr[j], acc[i][j], 0, 0, 0);
  }
  // write N1 strip transposed into LDS as [c_local][e] bf16
#pragma unroll
  for (int i = 0; i < 4; i++)
#pragma unroll
    for (int j = 0; j < 2; j++)
#pragma unroll
      for (int rg = 0; rg < 4; rg++) {
        int e = wave * 64 + i * 16 + quad * 4 + rg;
        int cl = j * 16 + col;
        N1b[cl * 264 + e] = f2bf(acc[i][j][rg]);
      }

  // ---- stage 4: T[:, cs..+32] = wp * N1^T ----
  f32x4 acc2[4][2];
#pragma unroll
  for (int i = 0; i < 4; i++)
#pragma unroll
    for (int j = 0; j < 2; j++) acc2[i][j] = (f32x4){0.f, 0.f, 0.f, 0.f};
  auto s4_load = [&](int buf, int kt) {
    ushort* L = (ushort*)(smem + buf * 18432);
#pragma unroll
    for (int q = 0; q < 4; q++)
      gld16(wp + (size_t)(q * 64 + rA) * 256 + kt + sub, L + (q * 256 + tid) * 8);
  };
  s4_load(0, 0);
  for (int it = 0; it < 8; ++it) {
    int cur = it & 1;
    __syncthreads();
    if (it + 1 < 8) s4_load(cur ^ 1, (it + 1) * 32);
    const ushort* lW = (const ushort*)(smem + cur * 18432);
    int kt = it * 32;
    bf16x8 af[4], bfr[2];
#pragma unroll
    for (int i = 0; i < 4; i++)
      af[i] = *(const bf16x8*)&lW[(wave * 64 + i * 16 + col) * 32 + quad * 8];
#pragma unroll
    for (int j = 0; j < 2; j++)
      bfr[j] = *(const bf16x8*)&N1b[(j * 16 + col) * 264 + kt + quad * 8];
#pragma unroll
    for (int i = 0; i < 4; i++)
#pragma unroll
      for (int j = 0; j < 2; j++)
        acc2[i][j] = __builtin_amdgcn_mfma_f32_16x16x32_bf16(af[i], bfr[j], acc2[i][j], 0, 0, 0);
  }
  __syncthreads();
  // epilogue via per-wave lCw (region0, disjoint from N1b)
  float* lCw = (float*)smem + wave * 576;
#pragma unroll
  for (int i = 0; i < 4; i++) {
#pragma unroll
    for (int j = 0; j < 2; j++)
#pragma unroll
      for (int rg = 0; rg < 4; rg++)
        lCw[(quad * 4 + rg) * 36 + j * 16 + col] = acc2[i][j][rg];
    int oW = wave * 64 + i * 16;
    int rr = lane >> 2, cc = (lane & 3) * 8;
    union { ushort u[8]; int4 v; } o;
#pragma unroll
    for (int t8 = 0; t8 < 8; t8++) o.u[t8] = f2bf(lCw[rr * 36 + cc + t8]);
    *(int4*)(Tm + (size_t)z * 65536 + (size_t)(oW + rr) * 256 + cs + cc) = o.v;
    int nn = lane >> 1, mh = (lane & 1) * 8;
    union { ushort u[8]; int4 v; } o2;
#pragma unroll
    for (int t8 = 0; t8 < 8; t8++) o2.u[t8] = f2bf(lCw[(mh + t8) * 36 + nn]);
    *(int4*)(TmT + (size_t)z * 65536 + (size_t)(cs + nn) * 256 + oW + mh) = o2.v;
  }
}

// ---------------- merged: dsq symmetric-pair tiles (blk<1280) + bo_d1 (blk>=1280) ----------------
// dsq: d2[o] = sum_{a<=b} (2-delta_ab) * sum_{k in a, n in b} T[o,k] G[n,k] T[o,n]
// G is exactly symmetric (gram writes both halves from identical values), 2*x exact in fp32.
__global__ __launch_bounds__(256)
void dsq_bo_kernel(const ushort* __restrict__ Tm, const ushort* __restrict__ Gh,
                   const ushort* __restrict__ Gl,
                   const ushort* __restrict__ wpT, const ushort* __restrict__ TmT,
                   const float* __restrict__ pb, const float* __restrict__ rb,
                   const float* __restrict__ bp, float* __restrict__ bo,
                   float* __restrict__ m_acc, float* __restrict__ v_acc) {
  __shared__ __align__(16) char smem[24576];
  int blk = blockIdx.x;
  int tid = threadIdx.x;
  if (blk >= 1280) {
    int z = blk - 1280;
    float* sp = (float*)smem;
    float* sr = sp + 256;
    sp[tid] = pb[z * 256 + tid];
    sr[tid] = rb[z * 256 + tid];
    __syncthreads();
    float bv = bp[tid], d1 = 0.f;
    const ushort* Tz = TmT + (size_t)z * 65536;
    for (int c = 0; c < 256; c++) {
      bv += bf2f(wpT[c * 256 + tid]) * sp[c];
      d1 += bf2f(Tz[c * 256 + tid]) * sr[c];
    }
    bo[z * 256 + tid] = bv;
    atomicAdd(m_acc + tid, d1 + 1600.0f * bv);
    atomicAdd(v_acc + tid, 2.0f * bv * d1 + 1600.0f * bv * bv);
    return;
  }
  // 1280 blocks = 8 XCD slots x 160; XCD k owns z in [4k,4k+4); 40 tiles/z = 4 m-tiles x 10 pairs
  int k8 = blk & 7, j9 = blk >> 3;         // j9 in [0,160)
  int z = 4 * k8 + j9 / 40;
  int rem = j9 % 40;
  int mt = rem / 10, t = rem % 10;
  int ty = (t >= 4) + (t >= 7) + (t >= 9);
  int base = ty * 4 - (ty * (ty - 1)) / 2;
  int tx = ty + (t - base);
  int mBase = mt * 64, aBase = ty * 64, bBase = tx * 64;   // a = k-tile, b = n-tile
  float mul = (tx == ty) ? 1.0f : 2.0f;
  int wave = tid >> 6, lane = tid & 63;
  int wm = wave >> 1, wn = wave & 1;
  int col = lane & 15, quad = lane >> 4;
  int srow = tid >> 2, skc = (tid & 3) * 8;
  const ushort* Tz = Tm + (size_t)z * 65536;
  const ushort* Ghz = Gh + (size_t)z * 65536;
  const ushort* Glz = Gl + (size_t)z * 65536;
  // stage: A = T[mBase..+64, aBase..+64]; B = Gh/Gl[bBase..+64, aBase..+64]; 2 chunks of k-32
  ushort* lA = (ushort*)smem;          // 2 x 2048 ushorts (8 KB)
  ushort* lH = lA + 4096;              // 8 KB
  ushort* lL = lH + 4096;              // 8 KB
#pragma unroll
  for (int c = 0; c < 2; c++) {
    int ko = aBase + c * 32 + skc;
    gld16(Tz + (size_t)(mBase + srow) * 256 + ko, lA + c * 2048 + tid * 8);
    gld16(Ghz + (size_t)(bBase + srow) * 256 + ko, lH + c * 2048 + tid * 8);
    gld16(Glz + (size_t)(bBase + srow) * 256 + ko, lL + c * 2048 + tid * 8);
  }
  f32x4 acc[2][2];
#pragma unroll
  for (int i = 0; i < 2; i++)
#pragma unroll
    for (int j = 0; j < 2; j++) acc[i][j] = (f32x4){0.f, 0.f, 0.f, 0.f};
  __syncthreads();
#pragma unroll
  for (int c = 0; c < 2; c++) {
    const ushort* cA = lA + c * 2048;
    const ushort* cH = lH + c * 2048;
    const ushort* cL = lL + c * 2048;
    bf16x8 af[2], bh[2], bl[2];
#pragma unroll
    for (int i = 0; i < 2; i++)
      af[i] = *(const bf16x8*)&cA[(wm * 32 + i * 16 + col) * 32 + quad * 8];
#pragma unroll
    for (int j = 0; j < 2; j++) {
      bh[j] = *(const bf16x8*)&cH[(wn * 32 + j * 16 + col) * 32 + quad * 8];
      bl[j] = *(const bf16x8*)&cL[(wn * 32 + j * 16 + col) * 32 + quad * 8];
    }
#pragma unroll
    for (int i = 0; i < 2; i++)
#pragma unroll
      for (int j = 0; j < 2; j++) {
        acc[i][j] = __builtin_amdgcn_mfma_f32_16x16x32_bf16(af[i], bh[j], acc[i][j], 0, 0, 0);
        acc[i][j] = __builtin_amdgcn_mfma_f32_16x16x32_bf16(af[i], bl[j], acc[i][j], 0, 0, 0);
      }
  }
  // rowdot with T[o, bBase + n], double off-diagonal pairs, atomic into v_acc
#pragma unroll
  for (int i = 0; i < 2; i++) {
    int mr = mBase + wm * 32 + i * 16 + quad * 4;
#pragma unroll
    for (int rg = 0; rg < 4; rg++) {
      float p = 0.f;
#pragma unroll
      for (int j = 0; j < 2; j++)
        p += acc[i][j][rg] * bf2f(Tz[(mr + rg) * 256 + bBase + wn * 32 + j * 16 + col]);
      p += __shfl_down(p, 8);
      p += __shfl_down(p, 4);
      p += __shfl_down(p, 2);
      p += __shfl_down(p, 1);
      if (col == 0) atomicAdd(v_acc + mr + rg, p * mul);
    }
  }
}

// ---------------- final: out = BN(T*X + bo), XCD z-grouped ----------------
__global__ __launch_bounds__(256)
void final_kernel(const ushort* __restrict__ Tm, const ushort* __restrict__ xT,
                  const float* __restrict__ bo, const float* __restrict__ m_acc,
                  const float* __restrict__ v_acc, const float* __restrict__ gq,
                  const float* __restrict__ beta, float* __restrict__ out) {
  __shared__ __align__(16) char smem[32768];
  float* lC = (float*)smem;
  // 832 blocks = 8 XCD slots x 104; XCD k owns z in [4k, 4k+4), 26 tiles/z
  int lin = blockIdx.x + 13 * blockIdx.y + 26 * blockIdx.z;
  int k8 = lin % 8, j9 = lin / 8;          // j9 in [0,104)
  int z = 4 * k8 + j9 / 26;
  int tile = j9 % 26;
  int mBase = (tile / 13) * 128, nBase = (tile % 13) * 128;
  int tid = threadIdx.x, wave = tid >> 6, lane = tid & 63;
  int wm = wave >> 1, wn = wave & 1;
  int col = lane & 15, quad = lane >> 4;
  int srow = tid >> 2, skc = (tid & 3) * 8;
  const ushort* Az = Tm + (size_t)z * 65536;
  const ushort* Bz = xT + (size_t)z * (NN * 256);
  const ushort* gA  = Az + (size_t)(mBase + srow) * 256 + skc;
  const ushort* gA2 = gA + 64 * 256;
  int br1 = nBase + srow;      br1 = br1 < NN ? br1 : NN - 1;
  int br2 = nBase + 64 + srow; br2 = br2 < NN ? br2 : NN - 1;
  const ushort* gB  = Bz + (size_t)br1 * 256 + skc;
  const ushort* gB2 = Bz + (size_t)br2 * 256 + skc;
  ushort* sA1[2]; ushort* sA2[2]; ushort* sB1[2]; ushort* sB2[2];
#pragma unroll
  for (int b = 0; b < 2; b++) {
    ushort* lAb = (ushort*)(smem + b * 16384);
    ushort* lBb = (ushort*)(smem + b * 16384 + 8192);
    sA1[b] = &lAb[srow * 32 + skc];
    sA2[b] = &lAb[(64 + srow) * 32 + skc];
    sB1[b] = &lBb[srow * 32 + skc];
    sB2[b] = &lBb[(64 + srow) * 32 + skc];
  }
  f32x4 acc[4][4];
#pragma unroll
  for (int i = 0; i < 4; i++)
#pragma unroll
    for (int j = 0; j < 4; j++) acc[i][j] = (f32x4){0.f, 0.f, 0.f, 0.f};

  const int nIter = 8;  // K=256
  gld16(gA, sA1[0]); gld16(gA2, sA2[0]); gld16(gB, sB1[0]); gld16(gB2, sB2[0]);
  for (int it = 0; it < nIter; ++it) {
    int cur = it & 1;
    __syncthreads();
    if (it + 1 < nIter) {
      int kt = (it + 1) << 5, nxt = cur ^ 1;
      gld16(gA + kt, sA1[nxt]); gld16(gA2 + kt, sA2[nxt]);
      gld16(gB + kt, sB1[nxt]); gld16(gB2 + kt, sB2[nxt]);
    }
    const ushort* lAc = (const ushort*)(smem + cur * 16384);
    const ushort* lBc = (const ushort*)(smem + cur * 16384 + 8192);
    bf16x8 af[4], bfr[4];
#pragma unroll
    for (int i = 0; i < 4; i++)
      af[i] = *(const bf16x8*)&lAc[(wm * 64 + i * 16 + col) * 32 + quad * 8];
#pragma unroll
    for (int j = 0; j < 4; j++)
      bfr[j] = *(const bf16x8*)&lBc[(wn * 64 + j * 16 + col) * 32 + quad * 8];
#pragma unroll
    for (int i = 0; i < 4; i++)
#pragma unroll
      for (int j = 0; j < 4; j++)
        acc[i][j] = __builtin_amdgcn_mfma_f32_16x16x32_bf16(af[i], bfr[j], acc[i][j], 0, 0, 0);
  }
  __syncthreads();
  float* lCw = lC + wave * 16 * 68;
  int mW = mBase + wm * 64, nW = nBase + wn * 64;
  int b = z >> 2, q = z & 3;
  const float inv = 1.0f / (float)SP;
#pragma unroll
  for (int i = 0; i < 4; i++) {
#pragma unroll
    for (int j = 0; j < 4; j++)
#pragma unroll
      for (int rg = 0; rg < 4; rg++)
        lCw[(quad * 4 + rg) * 68 + j * 16 + col] = acc[i][j][rg];
    int mrow0 = mW + i * 16;
    int rr = lane & 15, cc = lane >> 4;
    int n0 = nW + cc * 16;
    int o = mrow0 + rr;
    float bi = bo[(size_t)z * 256 + o];
    float mean = m_acc[o] * inv;
    float var = v_acc[o] * inv - mean * mean;
    float scl = rsqrtf(var + EPSF) * gq[o];
    float be = beta[o];
    if (n0 < NN) {
      float* C = out + (size_t)b * (CCH * QQ * NN)
               + (size_t)o * (QQ * NN) + (size_t)q * NN + n0;
#pragma unroll
      for (int v = 0; v < 4; v++) {
        float4 f;
        f.x = (lCw[rr * 68 + cc * 16 + v * 4 + 0] + bi - mean) * scl + be;
        f.y = (lCw[rr * 68 + cc * 16 + v * 4 + 1] + bi - mean) * scl + be;
        f.z = (lCw[rr * 68 + cc * 16 + v * 4 + 2] + bi - mean) * scl + be;
        f.w = (lCw[rr * 68 + cc * 16 + v * 4 + 3] + bi - mean) * scl + be;
        *(float4*)(C + v * 4) = f;
      }
    }
  }
}

extern "C" void kernel_launch(void* const* d_in, const int* in_sizes, int n_in,
                              void* d_out, int out_size, void* d_ws, size_t ws_size,
                              hipStream_t stream) {
  const float* x     = (const float*)d_in[0];
  const float* Wq    = (const float*)d_in[1];
  const float* bq    = (const float*)d_in[2];
  const float* Wk    = (const float*)d_in[3];
  const float* bk    = (const float*)d_in[4];
  const float* Wv    = (const float*)d_in[5];
  const float* bv    = (const float*)d_in[6];
  const float* Wp    = (const float*)d_in[7];
  const float* bp    = (const float*)d_in[8];
  const float* gamma = (const float*)d_in[9];
  const float* beta  = (const float*)d_in[10];
  float* out = (float*)d_out;

  ushort* h    = (ushort*)d_ws;
  ushort* wq   = h;                      // 65536 each
  ushort* wk   = wq + 65536;
  ushort* wp   = wk + 65536;
  ushort* wvT  = wp + 65536;
  ushort* wqT  = wvT + 65536;
  ushort* wkT  = wqT + 65536;
  ushort* wpT  = wkT + 65536;
  ushort* xb   = wpT + 65536;                   // [32][256][1600]
  ushort* xT   = xb + (size_t)BQN * CCH * NN;   // [51200][256]
  ushort* Gh   = xT + (size_t)BQN * CCH * NN;   // [32][256][256]
  ushort* Gl   = Gh + (size_t)BQN * 65536;
  ushort* P    = Gl + (size_t)BQN * 65536;
  ushort* Tm   = P + (size_t)BQN * 65536;
  ushort* TmT  = Tm + (size_t)BQN * 65536;
  float*  r    = (float*)(TmT + (size_t)BQN * 65536);  // 8192
  float*  u    = r + 8192;
  float*  vv   = u + 8192;
  float*  pb   = vv + 8192;
  float*  bo   = pb + 8192;
  float*  m_acc = bo + 8192;             // 256
  float*  v_acc = m_acc + 256;           // 256
  float*  gq   = v_acc + 256;            // 256
  float*  rpart = gq + 256;              // 32*25*256 = 204800

  // quant weights + prep x (independent, merged)
  qp_kernel<<<4225, 256, 0, stream>>>(Wq, Wk, Wv, Wp, gamma, x,
                                      wq, wk, wvT, wp, wqT, wkT, wpT, gq,
                                      xb, xT, rpart);
  // gram (10 upper-tri 64x64 tiles, LDS dbuf) + r-reduce/uv matvec slot, z-grouped
  gram_uv_kernel<<<dim3(11, BQN), 256, 0, stream>>>(xb, Gh, Gl, wqT, wkT,
                                                    rpart, r, u, vv);
  // fused: S strip = wq*G*wk^T + bias -> softmax -> P, pb (z-grouped on XCD)
  spk_kernel<<<dim3(8, BQN), 256, 0, stream>>>(wq, Gh, Gl, wk, u, vv, bq, bk, bv, P, pb);
  // fused: N1 col-strip = P*Wv -> T(:,strip) = wp*N1^T -> Tm, TmT (z-grouped on XCD)
  pt_kernel<<<dim3(8, BQN), 256, 0, stream>>>(P, wvT, wp, Tm, TmT, m_acc, v_acc);
  // merged: v_acc += diag(T G T^T) via symmetric pairs (z-grouped) | bo/d1 + stats terms
  dsq_bo_kernel<<<1312, 256, 0, stream>>>(Tm, Gh, Gl, wpT, TmT, pb, r, bp,
                                          bo, m_acc, v_acc);
  // out = BN(T * X^T + bo), fully fused (z-grouped)
  final_kernel<<<dim3(13, 2, BQN), 256, 0, stream>>>(Tm, xT, bo, m_acc, v_acc,
                                                     gq, beta, out);
}

// Round 9
// 239.448 us; speedup vs baseline: 1.1495x; 1.1495x over previous
//
#include <hip/hip_runtime.h>
#include <math.h>

#define BB 8
#define CCH 256
#define QQ 4
#define NN 1600          // H*W
#define BQN 32           // B*Q
#define SP 51200         // BQN*NN
#define EPSF 1e-5f

typedef __attribute__((ext_vector_type(8))) short bf16x8;  // 8 bf16 (4 VGPRs)
typedef __attribute__((ext_vector_type(4))) float f32x4;

static __device__ inline ushort f2bf(float f) {
  union { float f; unsigned u; } v; v.f = f;
  return (ushort)((v.u + 0x7fffu + ((v.u >> 16) & 1u)) >> 16);  // RNE
}
static __device__ inline float bf2f(ushort u) {
  union { unsigned u; float f; } v; v.u = ((unsigned)u) << 16;
  return v.f;
}
// async 16B global->LDS (lane-linear dest)
static __device__ inline void gld16(const ushort* g, ushort* l) {
  __builtin_amdgcn_global_load_lds(
      (const __attribute__((address_space(1))) unsigned int*)g,
      (__attribute__((address_space(3))) unsigned int*)l, 16, 0, 0);
}

// ---------------- merged: fake-quant weights (blk<1025) + prep x (blk>=1025) ----------------
__global__ __launch_bounds__(256)
void qp_kernel(const float* __restrict__ Wq, const float* __restrict__ Wk,
               const float* __restrict__ Wv, const float* __restrict__ Wp,
               const float* __restrict__ gamma, const float* __restrict__ x,
               ushort* __restrict__ wq, ushort* __restrict__ wk,
               ushort* __restrict__ wvT, ushort* __restrict__ wp,
               ushort* __restrict__ wqT, ushort* __restrict__ wkT,
               ushort* __restrict__ wpT, float* __restrict__ gq,
               ushort* __restrict__ xb, ushort* __restrict__ xT,
               float* __restrict__ rpart) {
  __shared__ float red[256];
  __shared__ ushort lT[64 * 66];
  int blk = blockIdx.x;
  int tid = threadIdx.x;
  if (blk < 1024) {
    int mat = blk >> 8;
    int row = blk & 255;
    const float* W = (mat == 0) ? Wq : (mat == 1) ? Wk : (mat == 2) ? Wv : Wp;
    float w = W[row * 256 + tid];
    red[tid] = fabsf(w);
    __syncthreads();
    for (int s = 128; s > 0; s >>= 1) {
      if (tid < s) red[tid] = fmaxf(red[tid], red[tid + s]);
      __syncthreads();
    }
    float s = red[0] / 127.0f + 1e-8f;
    float q = fminf(fmaxf(rintf(w / s), -127.0f), 127.0f) * s;
    ushort qb = f2bf(q);
    if (mat == 0)      { wq[row * 256 + tid] = qb; wqT[tid * 256 + row] = qb; }
    else if (mat == 1) { wk[row * 256 + tid] = qb; wkT[tid * 256 + row] = qb; }
    else if (mat == 2) { wvT[tid * 256 + row] = qb; }   // wvT[i][d]=Wv[d][i]
    else               { wp[row * 256 + tid] = qb; wpT[tid * 256 + row] = qb; }
    return;
  }
  if (blk == 1024) {
    float g = gamma[tid];
    red[tid] = fabsf(g);
    __syncthreads();
    for (int s = 128; s > 0; s >>= 1) {
      if (tid < s) red[tid] = fmaxf(red[tid], red[tid + s]);
      __syncthreads();
    }
    float s = red[0] / 127.0f + 1e-8f;
    gq[tid] = fminf(fmaxf(rintf(g / s), -127.0f), 127.0f) * s;
    return;
  }
  // ---- prep ----
  int p = blk - 1025;            // 0..3199
  int sx = p % 25;
  int rem = p / 25;              // 0..127
  int cy = rem & 3, bqi = rem >> 2;
  int b = bqi >> 2, q = bqi & 3;
  int s0 = sx * 64, c0 = cy * 64;
  int c = tid >> 2, nch = (tid & 3) * 16;
  const float* xp = x + ((size_t)(b * CCH + c0 + c) * QQ + q) * NN + s0 + nch;
  union { ushort u[16]; int4 v[2]; } nb;
  float s = 0.f;
#pragma unroll
  for (int j = 0; j < 4; j++) {
    float4 f = ((const float4*)xp)[j];
    ushort b0 = f2bf(f.x), b1 = f2bf(f.y), b2 = f2bf(f.z), b3 = f2bf(f.w);
    s += bf2f(b0) + bf2f(b1) + bf2f(b2) + bf2f(b3);
    nb.u[j * 4 + 0] = b0;
    nb.u[j * 4 + 1] = b1;
    nb.u[j * 4 + 2] = b2;
    nb.u[j * 4 + 3] = b3;
    lT[c * 66 + nch + j * 4 + 0] = b0;
    lT[c * 66 + nch + j * 4 + 1] = b1;
    lT[c * 66 + nch + j * 4 + 2] = b2;
    lT[c * 66 + nch + j * 4 + 3] = b3;
  }
  ushort* xbp = xb + (size_t)bqi * (CCH * NN) + (size_t)(c0 + c) * NN + s0 + nch;
  *(int4*)xbp = nb.v[0];
  *((int4*)xbp + 1) = nb.v[1];
  s += __shfl_down(s, 2);
  s += __shfl_down(s, 1);
  if ((tid & 3) == 0) rpart[((size_t)bqi * 25 + sx) * 256 + c0 + c] = s;
  __syncthreads();
  int n = tid >> 2, cch = (tid & 3) * 16;
  union { ushort u[16]; int4 v[2]; } o;
#pragma unroll
  for (int i = 0; i < 16; i++) o.u[i] = lT[(cch + i) * 66 + n];
  ushort* dst = xT + (size_t)(bqi * NN + s0 + n) * CCH + c0 + cch;
  *(int4*)dst = o.v[0];
  *((int4*)dst + 1) = o.v[1];
}

// ---------------- Gram (symmetric, LDS dbuf) + uv slot, XCD z-grouped ----------------
__global__ __launch_bounds__(256)
void gram_uv_kernel(const ushort* __restrict__ xb, ushort* __restrict__ Gh,
                    ushort* __restrict__ Gl,
                    const ushort* __restrict__ wqT, const ushort* __restrict__ wkT,
                    const float* __restrict__ rpart, float* __restrict__ r,
                    float* __restrict__ u, float* __restrict__ vv) {
  __shared__ __align__(16) char smem[16384];
  __shared__ float rs[256];
  // 352 blocks = 8 XCD slots x 44; XCD k owns z in [4k, 4k+4)
  int lin = blockIdx.x + 11 * blockIdx.y;
  int k8 = lin & 7, j = lin >> 3;          // j in [0,44)
  int z = 4 * k8 + j / 11, t = j % 11;
  int tid = threadIdx.x;
  if (t == 10) {
    float rv = 0.f;
#pragma unroll
    for (int k = 0; k < 25; k++) rv += rpart[((size_t)z * 25 + k) * 256 + tid];
    rs[tid] = rv;
    r[z * 256 + tid] = rv;
    __syncthreads();
    float su = 0.f, sv = 0.f;
    for (int i = 0; i < 256; i++) {
      float rr = rs[i];
      su += bf2f(wqT[i * 256 + tid]) * rr;
      sv += bf2f(wkT[i * 256 + tid]) * rr;
    }
    u[z * 256 + tid] = su;
    vv[z * 256 + tid] = sv;
    return;
  }
  int ty = (t >= 4) + (t >= 7) + (t >= 9);
  int base = ty * 4 - (ty * (ty - 1)) / 2;
  int tx = ty + (t - base);
  int mBase = ty * 64, nBase = tx * 64;
  bool offd = (tx != ty);
  int wave = tid >> 6, lane = tid & 63;
  int wm = wave >> 1, wn = wave & 1;
  int col = lane & 15, quad = lane >> 4;
  const ushort* X = xb + (size_t)z * (CCH * NN);
  const ushort* gA = X + (size_t)(mBase + (tid >> 2)) * NN + (tid & 3) * 8;
  const ushort* gB = X + (size_t)(nBase + (tid >> 2)) * NN + (tid & 3) * 8;
  f32x4 acc[2][2];
#pragma unroll
  for (int i = 0; i < 2; i++)
#pragma unroll
    for (int j2 = 0; j2 < 2; j2++) acc[i][j2] = (f32x4){0.f, 0.f, 0.f, 0.f};

  const int nIter = NN / 32;   // 50
  gld16(gA, (ushort*)smem + tid * 8);
  gld16(gB, (ushort*)(smem + 4096) + tid * 8);
  for (int it = 0; it < nIter; ++it) {
    int cur = it & 1;
    __syncthreads();
    if (it + 1 < nIter) {
      int kt = (it + 1) << 5;
      char* bb = smem + (cur ^ 1) * 8192;
      gld16(gA + kt, (ushort*)bb + tid * 8);
      gld16(gB + kt, (ushort*)(bb + 4096) + tid * 8);
    }
    const ushort* lA = (const ushort*)(smem + cur * 8192);
    const ushort* lB = lA + 2048;
    bf16x8 af[2], bfr[2];
#pragma unroll
    for (int i = 0; i < 2; i++)
      af[i] = *(const bf16x8*)&lA[(wm * 32 + i * 16 + col) * 32 + quad * 8];
#pragma unroll
    for (int j2 = 0; j2 < 2; j2++)
      bfr[j2] = *(const bf16x8*)&lB[(wn * 32 + j2 * 16 + col) * 32 + quad * 8];
#pragma unroll
    for (int i = 0; i < 2; i++)
#pragma unroll
      for (int j2 = 0; j2 < 2; j2++)
        acc[i][j2] = __builtin_amdgcn_mfma_f32_16x16x32_bf16(af[i], bfr[j2], acc[i][j2], 0, 0, 0);
  }
  __syncthreads();
  float* lCw = (float*)smem + wave * 576;
#pragma unroll
  for (int i = 0; i < 2; i++) {
#pragma unroll
    for (int j2 = 0; j2 < 2; j2++)
#pragma unroll
      for (int rg = 0; rg < 4; rg++)
        lCw[(quad * 4 + rg) * 36 + j2 * 16 + col] = acc[i][j2][rg];
    int mrow0 = mBase + wm * 32 + i * 16;
    int nW = nBase + wn * 32;
    int rr = lane >> 2, cc = (lane & 3) * 8;
    union { ushort u[8]; int4 v; } oh, ol;
#pragma unroll
    for (int t8 = 0; t8 < 8; t8++) {
      float vfl = lCw[rr * 36 + cc + t8];
      ushort hh = f2bf(vfl);
      oh.u[t8] = hh;
      ol.u[t8] = f2bf(vfl - bf2f(hh));
    }
    size_t off = (size_t)z * 65536 + (size_t)(mrow0 + rr) * 256 + nW + cc;
    *(int4*)(Gh + off) = oh.v;
    *(int4*)(Gl + off) = ol.v;
    if (offd) {
      int nn = lane >> 1, mh = (lane & 1) * 8;
      union { ushort u[8]; int4 v; } th, tl;
#pragma unroll
      for (int t8 = 0; t8 < 8; t8++) {
        float vfl = lCw[(mh + t8) * 36 + nn];
        ushort hh = f2bf(vfl);
        th.u[t8] = hh;
        tl.u[t8] = f2bf(vfl - bf2f(hh));
      }
      size_t offT = (size_t)z * 65536 + (size_t)(nW + nn) * 256 + mrow0 + mh;
      *(int4*)(Gh + offT) = th.v;
      *(int4*)(Gl + offT) = tl.v;
    }
  }
}

// ---------------- fused S-path, single-buffered staging (68.6KB LDS -> 2 blocks/CU), z-grouped ----------------
__global__ __launch_bounds__(256)
void spk_kernel(const ushort* __restrict__ wq, const ushort* __restrict__ Gh,
                const ushort* __restrict__ Gl, const ushort* __restrict__ wk,
                const float* __restrict__ ug, const float* __restrict__ vg,
                const float* __restrict__ bqv, const float* __restrict__ bkv,
                const float* __restrict__ bvv,
                ushort* __restrict__ P, float* __restrict__ pb) {
  // staging 34816 B @0 (A 2048 | Bh 16384 @+2048 | Bl 16384 @+18432)
  // M1h @34816 (16896B) + M1l @51712 (16896B); M1 region reused as Sb 32x260 f32
  __shared__ __align__(16) char smem[68608];
  int lin = blockIdx.x + 8 * blockIdx.y;
  int k8 = lin & 7, j9 = lin >> 3;         // j9 in [0,32)
  int z = 4 * k8 + (j9 >> 3), mBase = (j9 & 7) * 32;
  int tid = threadIdx.x, wave = tid >> 6, lane = tid & 63;
  int col = lane & 15, quad = lane >> 4;
  int rA = tid >> 2, sub = (tid & 3) * 8;
  const ushort* Ghz = Gh + (size_t)z * 65536;
  const ushort* Glz = Gl + (size_t)z * 65536;
  ushort* M1h_l = (ushort*)(smem + 34816);
  ushort* M1l_l = M1h_l + 8448;

  // ---- stage 1: M1 strip = wq[mBase..+32] * (Gh+Gl)^T ----
  f32x4 acc[2][4];
#pragma unroll
  for (int i = 0; i < 2; i++)
#pragma unroll
    for (int j = 0; j < 4; j++) acc[i][j] = (f32x4){0.f, 0.f, 0.f, 0.f};

  auto s1_load = [&](int kt) {
    ushort* L = (ushort*)smem;
    if (tid < 128)
      gld16(wq + (size_t)(mBase + rA) * 256 + kt + sub, L + tid * 8);
    ushort* Lh = L + 1024;
    ushort* Ll = L + 9216;
#pragma unroll
    for (int q = 0; q < 4; q++) {
      int n = q * 64 + rA;
      gld16(Ghz + (size_t)n * 256 + kt + sub, Lh + (q * 256 + tid) * 8);
      gld16(Glz + (size_t)n * 256 + kt + sub, Ll + (q * 256 + tid) * 8);
    }
  };
  for (int it = 0; it < 8; ++it) {
    if (it) __syncthreads();          // prev compute done before overwrite
    s1_load(it * 32);
    __syncthreads();                  // drains vmcnt -> staged data visible
    const ushort* L = (const ushort*)smem;
    const ushort* lA = L;
    const ushort* lBh = L + 1024;
    const ushort* lBl = L + 9216;
    bf16x8 af[2], bh[4], bl[4];
#pragma unroll
    for (int i = 0; i < 2; i++)
      af[i] = *(const bf16x8*)&lA[(i * 16 + col) * 32 + quad * 8];
#pragma unroll
    for (int j = 0; j < 4; j++) {
      bh[j] = *(const bf16x8*)&lBh[(wave * 64 + j * 16 + col) * 32 + quad * 8];
      bl[j] = *(const bf16x8*)&lBl[(wave * 64 + j * 16 + col) * 32 + quad * 8];
    }
#pragma unroll
    for (int i = 0; i < 2; i++)
#pragma unroll
      for (int j = 0; j < 4; j++) {
        acc[i][j] = __builtin_amdgcn_mfma_f32_16x16x32_bf16(af[i], bh[j], acc[i][j], 0, 0, 0);
        acc[i][j] = __builtin_amdgcn_mfma_f32_16x16x32_bf16(af[i], bl[j], acc[i][j], 0, 0, 0);
      }
  }
  // split M1 to bf16 hi/lo in LDS (M1 region disjoint from staging)
#pragma unroll
  for (int i = 0; i < 2; i++)
#pragma unroll
    for (int j = 0; j < 4; j++)
#pragma unroll
      for (int rg = 0; rg < 4; rg++) {
        int ml = i * 16 + quad * 4 + rg;
        int cg = wave * 64 + j * 16 + col;
        float vfl = acc[i][j][rg];
        ushort hh = f2bf(vfl);
        M1h_l[ml * 264 + cg] = hh;
        M1l_l[ml * 264 + cg] = f2bf(vfl - bf2f(hh));
      }
  __syncthreads();   // M1 visible; all stage-1 staging reads complete

  // ---- stage 2: S strip = (M1h + M1l) * wk^T ----
  f32x4 acc2[2][4];
#pragma unroll
  for (int i = 0; i < 2; i++)
#pragma unroll
    for (int j = 0; j < 4; j++) acc2[i][j] = (f32x4){0.f, 0.f, 0.f, 0.f};
  auto s2_load = [&](int kt) {
    ushort* L = (ushort*)smem;
#pragma unroll
    for (int q = 0; q < 4; q++)
      gld16(wk + (size_t)(q * 64 + rA) * 256 + kt + sub, L + (q * 256 + tid) * 8);
  };
  for (int it = 0; it < 8; ++it) {
    if (it) __syncthreads();
    s2_load(it * 32);
    __syncthreads();
    const ushort* lB = (const ushort*)smem;
    int kt = it * 32;
    bf16x8 ah[2], al[2], bfr[4];
#pragma unroll
    for (int i = 0; i < 2; i++) {
      ah[i] = *(const bf16x8*)&M1h_l[(i * 16 + col) * 264 + kt + quad * 8];
      al[i] = *(const bf16x8*)&M1l_l[(i * 16 + col) * 264 + kt + quad * 8];
    }
#pragma unroll
    for (int j = 0; j < 4; j++)
      bfr[j] = *(const bf16x8*)&lB[(wave * 64 + j * 16 + col) * 32 + quad * 8];
#pragma unroll
    for (int i = 0; i < 2; i++)
#pragma unroll
      for (int j = 0; j < 4; j++) {
        acc2[i][j] = __builtin_amdgcn_mfma_f32_16x16x32_bf16(ah[i], bfr[j], acc2[i][j], 0, 0, 0);
        acc2[i][j] = __builtin_amdgcn_mfma_f32_16x16x32_bf16(al[i], bfr[j], acc2[i][j], 0, 0, 0);
      }
  }
  __syncthreads();   // all waves done reading M1 LDS before overwrite with Sb

  // ---- bias + store S strip to LDS ----
  float* Sb = (float*)(smem + 34816);   // 32 x 260 f32
  float bkc[4], vvc[4];
#pragma unroll
  for (int j = 0; j < 4; j++) {
    int cg = wave * 64 + j * 16 + col;
    bkc[j] = bkv[cg];
    vvc[j] = vg[z * 256 + cg];
  }
#pragma unroll
  for (int i = 0; i < 2; i++)
#pragma unroll
    for (int rg = 0; rg < 4; rg++) {
      int ml = i * 16 + quad * 4 + rg;
      int rglob = mBase + ml;
      float uu = ug[z * 256 + rglob];
      float bqc = bqv[rglob];
#pragma unroll
      for (int j = 0; j < 4; j++)
        Sb[ml * 260 + wave * 64 + j * 16 + col] =
            0.125f * (acc2[i][j][rg] + uu * bkc[j] + bqc * vvc[j] + 1600.0f * bqc * bkc[j]);
    }
  __syncthreads();

  // ---- wave-parallel softmax: 8 rows per wave ----
  float4 bv4 = *(const float4*)(bvv + lane * 4);
#pragma unroll
  for (int rr8 = 0; rr8 < 8; ++rr8) {
    int rloc = wave * 8 + rr8;
    f32x4 sv = *(const f32x4*)&Sb[rloc * 260 + lane * 4];
    float x0 = sv[0], x1 = sv[1], x2 = sv[2], x3 = sv[3];
    float m = fmaxf(fmaxf(x0, x1), fmaxf(x2, x3));
#pragma unroll
    for (int s = 32; s > 0; s >>= 1) m = fmaxf(m, __shfl_xor(m, s));
    float e0 = expf(x0 - m), e1 = expf(x1 - m), e2 = expf(x2 - m), e3 = expf(x3 - m);
    float t = e0 + e1 + e2 + e3;
#pragma unroll
    for (int s = 32; s > 0; s >>= 1) t += __shfl_xor(t, s);
    float is = 1.0f / t;
    float p0 = e0 * is, p1 = e1 * is, p2 = e2 * is, p3 = e3 * is;
    union { ushort u[4]; uint2 v; } o;
    o.u[0] = f2bf(p0); o.u[1] = f2bf(p1); o.u[2] = f2bf(p2); o.u[3] = f2bf(p3);
    *(uint2*)(P + (size_t)z * 65536 + (size_t)(mBase + rloc) * 256 + lane * 4) = o.v;
    float d = p0 * bv4.x + p1 * bv4.y + p2 * bv4.z + p3 * bv4.w;
#pragma unroll
    for (int s = 32; s > 0; s >>= 1) d += __shfl_xor(d, s);
    if (lane == 0) pb[z * 256 + mBase + rloc] = d;
  }
}

// ---------------- fused T-path (R2/R5 body), XCD z-grouped ----------------
__global__ __launch_bounds__(256)
void pt_kernel(const ushort* __restrict__ P, const ushort* __restrict__ wvT,
               const ushort* __restrict__ wp,
               ushort* __restrict__ Tm, ushort* __restrict__ TmT,
               float* __restrict__ m_acc, float* __restrict__ v_acc) {
  // region0: staging dbuf 2 x 18432 B (big tile 16384 | small tile 2048 @+16384)
  // region1 @36864: N1buf 32x264 bf16 (16896B)
  __shared__ __align__(16) char smem[53760];
  int lin = blockIdx.x + 8 * blockIdx.y;
  int k8 = lin & 7, j9 = lin >> 3;
  int z = 4 * k8 + (j9 >> 3), cs = (j9 & 7) * 32;
  int tid = threadIdx.x, wave = tid >> 6, lane = tid & 63;
  int col = lane & 15, quad = lane >> 4;
  int rA = tid >> 2, sub = (tid & 3) * 8;
  if (lin == 0) {    // zero stats accumulators (read only after this kernel completes)
    m_acc[tid] = 0.f;
    v_acc[tid] = 0.f;
  }
  const ushort* Pz = P + (size_t)z * 65536;
  ushort* N1b = (ushort*)(smem + 36864);

  // ---- stage 3: N1[e, cs..+32] = P * Wv(:,cs..+32) ----
  f32x4 acc[4][2];
#pragma unroll
  for (int i = 0; i < 4; i++)
#pragma unroll
    for (int j = 0; j < 2; j++) acc[i][j] = (f32x4){0.f, 0.f, 0.f, 0.f};
  auto s3_load = [&](int buf, int kt) {
    ushort* L = (ushort*)(smem + buf * 18432);
#pragma unroll
    for (int q = 0; q < 4; q++)
      gld16(Pz + (size_t)(q * 64 + rA) * 256 + kt + sub, L + (q * 256 + tid) * 8);
    if (tid < 128)
      gld16(wvT + (size_t)(cs + rA) * 256 + kt + sub, L + 8192 + tid * 8);
  };
  s3_load(0, 0);
  for (int it = 0; it < 8; ++it) {
    int cur = it & 1;
    __syncthreads();
    if (it + 1 < 8) s3_load(cur ^ 1, (it + 1) * 32);
    const ushort* lP = (const ushort*)(smem + cur * 18432);
    const ushort* lV = lP + 8192;
    bf16x8 af[4], bfr[2];
#pragma unroll
    for (int i = 0; i < 4; i++)
      af[i] = *(const bf16x8*)&lP[(wave * 64 + i * 16 + col) * 32 + quad * 8];
#pragma unroll
    for (int j = 0; j < 2; j++)
      bfr[j] = *(const bf16x8*)&lV[(j * 16 + col) * 32 + quad * 8];
#pragma unroll
    for (int i = 0; i < 4; i++)
#pragma unroll
      for (int j = 0; j < 2; j++)
        acc[i][j] = __builtin_amdgcn_mfma_f32_16x16x32_bf16(af[i], bfr[j], acc[i][j], 0, 0, 0);
  }
  // write N1 strip transposed into LDS as [c_local][e] bf16
#pragma unroll
  for (int i = 0; i < 4; i++)
#pragma unroll
    for (int j = 0; j < 2; j++)
#pragma unroll
      for (int rg = 0; rg < 4; rg++) {
        int e = wave * 64 + i * 16 + quad * 4 + rg;
        int cl = j * 16 + col;
        N1b[cl * 264 + e] = f2bf(acc[i][j][rg]);
      }

  // ---- stage 4: T[:, cs..+32] = wp * N1^T ----
  f32x4 acc2[4][2];
#pragma unroll
  for (int i = 0; i < 4; i++)
#pragma unroll
    for (int j = 0; j < 2; j++) acc2[i][j] = (f32x4){0.f, 0.f, 0.f, 0.f};
  auto s4_load = [&](int buf, int kt) {
    ushort* L = (ushort*)(smem + buf * 18432);
#pragma unroll
    for (int q = 0; q < 4; q++)
      gld16(wp + (size_t)(q * 64 + rA) * 256 + kt + sub, L + (q * 256 + tid) * 8);
  };
  s4_load(0, 0);
  for (int it = 0; it < 8; ++it) {
    int cur = it & 1;
    __syncthreads();
    if (it + 1 < 8) s4_load(cur ^ 1, (it + 1) * 32);
    const ushort* lW = (const ushort*)(smem + cur * 18432);
    int kt = it * 32;
    bf16x8 af[4], bfr[2];
#pragma unroll
    for (int i = 0; i < 4; i++)
      af[i] = *(const bf16x8*)&lW[(wave * 64 + i * 16 + col) * 32 + quad * 8];
#pragma unroll
    for (int j = 0; j < 2; j++)
      bfr[j] = *(const bf16x8*)&N1b[(j * 16 + col) * 264 + kt + quad * 8];
#pragma unroll
    for (int i = 0; i < 4; i++)
#pragma unroll
      for (int j = 0; j < 2; j++)
        acc2[i][j] = __builtin_amdgcn_mfma_f32_16x16x32_bf16(af[i], bfr[j], acc2[i][j], 0, 0, 0);
  }
  __syncthreads();
  // epilogue via per-wave lCw (region0, disjoint from N1b)
  float* lCw = (float*)smem + wave * 576;
#pragma unroll
  for (int i = 0; i < 4; i++) {
#pragma unroll
    for (int j = 0; j < 2; j++)
#pragma unroll
      for (int rg = 0; rg < 4; rg++)
        lCw[(quad * 4 + rg) * 36 + j * 16 + col] = acc2[i][j][rg];
    int oW = wave * 64 + i * 16;
    int rr = lane >> 2, cc = (lane & 3) * 8;
    union { ushort u[8]; int4 v; } o;
#pragma unroll
    for (int t8 = 0; t8 < 8; t8++) o.u[t8] = f2bf(lCw[rr * 36 + cc + t8]);
    *(int4*)(Tm + (size_t)z * 65536 + (size_t)(oW + rr) * 256 + cs + cc) = o.v;
    int nn = lane >> 1, mh = (lane & 1) * 8;
    union { ushort u[8]; int4 v; } o2;
#pragma unroll
    for (int t8 = 0; t8 < 8; t8++) o2.u[t8] = f2bf(lCw[(mh + t8) * 36 + nn]);
    *(int4*)(TmT + (size_t)z * 65536 + (size_t)(cs + nn) * 256 + oW + mh) = o2.v;
  }
}

// ---------------- merged: dsq (blk<512, LDS-staged, XCD z-grouped) + bo_d1 (blk>=512) ----------------
__global__ __launch_bounds__(256)
void dsq_bo_kernel(const ushort* __restrict__ Tm, const ushort* __restrict__ Gh,
                   const ushort* __restrict__ Gl,
                   const ushort* __restrict__ wpT, const ushort* __restrict__ TmT,
                   const float* __restrict__ pb, const float* __restrict__ rb,
                   const float* __restrict__ bp, float* __restrict__ bo,
                   float* __restrict__ m_acc, float* __restrict__ v_acc) {
  __shared__ __align__(16) char smem[24576];
  int blk = blockIdx.x;
  int tid = threadIdx.x;
  if (blk >= 512) {
    int z = blk - 512;
    float* sp = (float*)smem;
    float* sr = sp + 256;
    sp[tid] = pb[z * 256 + tid];
    sr[tid] = rb[z * 256 + tid];
    __syncthreads();
    float bv = bp[tid], d1 = 0.f;
    const ushort* Tz = TmT + (size_t)z * 65536;
    for (int c = 0; c < 256; c++) {
      bv += bf2f(wpT[c * 256 + tid]) * sp[c];
      d1 += bf2f(Tz[c * 256 + tid]) * sr[c];
    }
    bo[z * 256 + tid] = bv;
    atomicAdd(m_acc + tid, d1 + 1600.0f * bv);
    atomicAdd(v_acc + tid, 2.0f * bv * d1 + 1600.0f * bv * bv);
    return;
  }
  // 512 blocks = 8 XCD slots x 64; XCD k owns z in [4k, 4k+4), 16 tiles/z
  int k8 = blk & 7, j9 = blk >> 3;         // j9 in [0,64)
  int z = 4 * k8 + (j9 >> 4);
  int tile = j9 & 15;
  int mBase = (tile >> 2) * 64, nBase = (tile & 3) * 64;
  int wave = tid >> 6, lane = tid & 63;
  int wm = wave >> 1, wn = wave & 1;
  int col = lane & 15, quad = lane >> 4;
  int srow = tid >> 2, skc = (tid & 3) * 8;
  const ushort* Tz = Tm + (size_t)z * 65536;
  const ushort* gA = Tz + (size_t)(mBase + srow) * 256 + skc;
  const ushort* gB = Gh + (size_t)z * 65536 + (size_t)(nBase + srow) * 256 + skc;
  const ushort* gX = Gl + (size_t)z * 65536 + (size_t)(nBase + srow) * 256 + skc;

  f32x4 acc[2][2];
#pragma unroll
  for (int i = 0; i < 2; i++)
#pragma unroll
    for (int j = 0; j < 2; j++) acc[i][j] = (f32x4){0.f, 0.f, 0.f, 0.f};

  {
    char* bb = smem;
    gld16(gA, (ushort*)bb + tid * 8);
    gld16(gB, (ushort*)(bb + 4096) + tid * 8);
    gld16(gX, (ushort*)(bb + 8192) + tid * 8);
  }
  for (int it = 0; it < 8; ++it) {
    int cur = it & 1;
    __syncthreads();
    if (it + 1 < 8) {
      int kt = (it + 1) * 32;
      char* bb = smem + (cur ^ 1) * 12288;
      gld16(gA + kt, (ushort*)bb + tid * 8);
      gld16(gB + kt, (ushort*)(bb + 4096) + tid * 8);
      gld16(gX + kt, (ushort*)(bb + 8192) + tid * 8);
    }
    const ushort* lA = (const ushort*)(smem + cur * 12288);
    const ushort* lB = lA + 2048;
    const ushort* lX = lA + 4096;
    bf16x8 af[2], bfv[2], xf[2];
#pragma unroll
    for (int i = 0; i < 2; i++)
      af[i] = *(const bf16x8*)&lA[(wm * 32 + i * 16 + col) * 32 + quad * 8];
#pragma unroll
    for (int j = 0; j < 2; j++) {
      bfv[j] = *(const bf16x8*)&lB[(wn * 32 + j * 16 + col) * 32 + quad * 8];
      xf[j]  = *(const bf16x8*)&lX[(wn * 32 + j * 16 + col) * 32 + quad * 8];
    }
#pragma unroll
    for (int i = 0; i < 2; i++)
#pragma unroll
      for (int j = 0; j < 2; j++) {
        acc[i][j] = __builtin_amdgcn_mfma_f32_16x16x32_bf16(af[i], bfv[j], acc[i][j], 0, 0, 0);
        acc[i][j] = __builtin_amdgcn_mfma_f32_16x16x32_bf16(af[i], xf[j], acc[i][j], 0, 0, 0);
      }
  }
#pragma unroll
  for (int i = 0; i < 2; i++) {
    int mr = mBase + wm * 32 + i * 16 + quad * 4;
#pragma unroll
    for (int rg = 0; rg < 4; rg++) {
      float p = 0.f;
#pragma unroll
      for (int j = 0; j < 2; j++)
        p += acc[i][j][rg] * bf2f(Tz[(mr + rg) * 256 + nBase + wn * 32 + j * 16 + col]);
      p += __shfl_down(p, 8);
      p += __shfl_down(p, 4);
      p += __shfl_down(p, 2);
      p += __shfl_down(p, 1);
      if (col == 0) atomicAdd(v_acc + mr + rg, p);
    }
  }
}

// ---------------- final: out = BN(T*X + bo), XCD z-grouped ----------------
__global__ __launch_bounds__(256)
void final_kernel(const ushort* __restrict__ Tm, const ushort* __restrict__ xT,
                  const float* __restrict__ bo, const float* __restrict__ m_acc,
                  const float* __restrict__ v_acc, const float* __restrict__ gq,
                  const float* __restrict__ beta, float* __restrict__ out) {
  __shared__ __align__(16) char smem[32768];
  float* lC = (float*)smem;
  // 832 blocks = 8 XCD slots x 104; XCD k owns z in [4k, 4k+4), 26 tiles/z
  int lin = blockIdx.x + 13 * blockIdx.y + 26 * blockIdx.z;
  int k8 = lin % 8, j9 = lin / 8;          // j9 in [0,104)
  int z = 4 * k8 + j9 / 26;
  int tile = j9 % 26;
  int mBase = (tile / 13) * 128, nBase = (tile % 13) * 128;
  int tid = threadIdx.x, wave = tid >> 6, lane = tid & 63;
  int wm = wave >> 1, wn = wave & 1;
  int col = lane & 15, quad = lane >> 4;
  int srow = tid >> 2, skc = (tid & 3) * 8;
  const ushort* Az = Tm + (size_t)z * 65536;
  const ushort* Bz = xT + (size_t)z * (NN * 256);
  const ushort* gA  = Az + (size_t)(mBase + srow) * 256 + skc;
  const ushort* gA2 = gA + 64 * 256;
  int br1 = nBase + srow;      br1 = br1 < NN ? br1 : NN - 1;
  int br2 = nBase + 64 + srow; br2 = br2 < NN ? br2 : NN - 1;
  const ushort* gB  = Bz + (size_t)br1 * 256 + skc;
  const ushort* gB2 = Bz + (size_t)br2 * 256 + skc;
  ushort* sA1[2]; ushort* sA2[2]; ushort* sB1[2]; ushort* sB2[2];
#pragma unroll
  for (int b = 0; b < 2; b++) {
    ushort* lAb = (ushort*)(smem + b * 16384);
    ushort* lBb = (ushort*)(smem + b * 16384 + 8192);
    sA1[b] = &lAb[srow * 32 + skc];
    sA2[b] = &lAb[(64 + srow) * 32 + skc];
    sB1[b] = &lBb[srow * 32 + skc];
    sB2[b] = &lBb[(64 + srow) * 32 + skc];
  }
  f32x4 acc[4][4];
#pragma unroll
  for (int i = 0; i < 4; i++)
#pragma unroll
    for (int j = 0; j < 4; j++) acc[i][j] = (f32x4){0.f, 0.f, 0.f, 0.f};

  const int nIter = 8;  // K=256
  gld16(gA, sA1[0]); gld16(gA2, sA2[0]); gld16(gB, sB1[0]); gld16(gB2, sB2[0]);
  for (int it = 0; it < nIter; ++it) {
    int cur = it & 1;
    __syncthreads();
    if (it + 1 < nIter) {
      int kt = (it + 1) << 5, nxt = cur ^ 1;
      gld16(gA + kt, sA1[nxt]); gld16(gA2 + kt, sA2[nxt]);
      gld16(gB + kt, sB1[nxt]); gld16(gB2 + kt, sB2[nxt]);
    }
    const ushort* lAc = (const ushort*)(smem + cur * 16384);
    const ushort* lBc = (const ushort*)(smem + cur * 16384 + 8192);
    bf16x8 af[4], bfr[4];
#pragma unroll
    for (int i = 0; i < 4; i++)
      af[i] = *(const bf16x8*)&lAc[(wm * 64 + i * 16 + col) * 32 + quad * 8];
#pragma unroll
    for (int j = 0; j < 4; j++)
      bfr[j] = *(const bf16x8*)&lBc[(wn * 64 + j * 16 + col) * 32 + quad * 8];
#pragma unroll
    for (int i = 0; i < 4; i++)
#pragma unroll
      for (int j = 0; j < 4; j++)
        acc[i][j] = __builtin_amdgcn_mfma_f32_16x16x32_bf16(af[i], bfr[j], acc[i][j], 0, 0, 0);
  }
  __syncthreads();
  float* lCw = lC + wave * 16 * 68;
  int mW = mBase + wm * 64, nW = nBase + wn * 64;
  int b = z >> 2, q = z & 3;
  const float inv = 1.0f / (float)SP;
#pragma unroll
  for (int i = 0; i < 4; i++) {
#pragma unroll
    for (int j = 0; j < 4; j++)
#pragma unroll
      for (int rg = 0; rg < 4; rg++)
        lCw[(quad * 4 + rg) * 68 + j * 16 + col] = acc[i][j][rg];
    int mrow0 = mW + i * 16;
    int rr = lane & 15, cc = lane >> 4;
    int n0 = nW + cc * 16;
    int o = mrow0 + rr;
    float bi = bo[(size_t)z * 256 + o];
    float mean = m_acc[o] * inv;
    float var = v_acc[o] * inv - mean * mean;
    float scl = rsqrtf(var + EPSF) * gq[o];
    float be = beta[o];
    if (n0 < NN) {
      float* C = out + (size_t)b * (CCH * QQ * NN)
               + (size_t)o * (QQ * NN) + (size_t)q * NN + n0;
#pragma unroll
      for (int v = 0; v < 4; v++) {
        float4 f;
        f.x = (lCw[rr * 68 + cc * 16 + v * 4 + 0] + bi - mean) * scl + be;
        f.y = (lCw[rr * 68 + cc * 16 + v * 4 + 1] + bi - mean) * scl + be;
        f.z = (lCw[rr * 68 + cc * 16 + v * 4 + 2] + bi - mean) * scl + be;
        f.w = (lCw[rr * 68 + cc * 16 + v * 4 + 3] + bi - mean) * scl + be;
        *(float4*)(C + v * 4) = f;
      }
    }
  }
}

extern "C" void kernel_launch(void* const* d_in, const int* in_sizes, int n_in,
                              void* d_out, int out_size, void* d_ws, size_t ws_size,
                              hipStream_t stream) {
  const float* x     = (const float*)d_in[0];
  const float* Wq    = (const float*)d_in[1];
  const float* bq    = (const float*)d_in[2];
  const float* Wk    = (const float*)d_in[3];
  const float* bk    = (const float*)d_in[4];
  const float* Wv    = (const float*)d_in[5];
  const float* bv    = (const float*)d_in[6];
  const float* Wp    = (const float*)d_in[7];
  const float* bp    = (const float*)d_in[8];
  const float* gamma = (const float*)d_in[9];
  const float* beta  = (const float*)d_in[10];
  float* out = (float*)d_out;

  ushort* h    = (ushort*)d_ws;
  ushort* wq   = h;                      // 65536 each
  ushort* wk   = wq + 65536;
  ushort* wp   = wk + 65536;
  ushort* wvT  = wp + 65536;
  ushort* wqT  = wvT + 65536;
  ushort* wkT  = wqT + 65536;
  ushort* wpT  = wkT + 65536;
  ushort* xb   = wpT + 65536;                   // [32][256][1600]
  ushort* xT   = xb + (size_t)BQN * CCH * NN;   // [51200][256]
  ushort* Gh   = xT + (size_t)BQN * CCH * NN;   // [32][256][256]
  ushort* Gl   = Gh + (size_t)BQN * 65536;
  ushort* P    = Gl + (size_t)BQN * 65536;
  ushort* Tm   = P + (size_t)BQN * 65536;
  ushort* TmT  = Tm + (size_t)BQN * 65536;
  float*  r    = (float*)(TmT + (size_t)BQN * 65536);  // 8192
  float*  u    = r + 8192;
  float*  vv   = u + 8192;
  float*  pb   = vv + 8192;
  float*  bo   = pb + 8192;
  float*  m_acc = bo + 8192;             // 256
  float*  v_acc = m_acc + 256;           // 256
  float*  gq   = v_acc + 256;            // 256
  float*  rpart = gq + 256;              // 32*25*256 = 204800

  // quant weights + prep x (independent, merged)
  qp_kernel<<<4225, 256, 0, stream>>>(Wq, Wk, Wv, Wp, gamma, x,
                                      wq, wk, wvT, wp, wqT, wkT, wpT, gq,
                                      xb, xT, rpart);
  // gram (10 upper-tri 64x64 tiles, LDS dbuf) + r-reduce/uv matvec slot, z-grouped
  gram_uv_kernel<<<dim3(11, BQN), 256, 0, stream>>>(xb, Gh, Gl, wqT, wkT,
                                                    rpart, r, u, vv);
  // fused: S strip = wq*G*wk^T + bias -> softmax -> P, pb (z-grouped, 2 blocks/CU)
  spk_kernel<<<dim3(8, BQN), 256, 0, stream>>>(wq, Gh, Gl, wk, u, vv, bq, bk, bv, P, pb);
  // fused: N1 col-strip = P*Wv -> T(:,strip) = wp*N1^T -> Tm, TmT (z-grouped on XCD)
  pt_kernel<<<dim3(8, BQN), 256, 0, stream>>>(P, wvT, wp, Tm, TmT, m_acc, v_acc);
  // merged: v_acc += diag(T G T^T) (z-grouped) | bo/d1 + mean/var terms
  dsq_bo_kernel<<<544, 256, 0, stream>>>(Tm, Gh, Gl, wpT, TmT, pb, r, bp,
                                         bo, m_acc, v_acc);
  // out = BN(T * X^T + bo), fully fused (z-grouped)
  final_kernel<<<dim3(13, 2, BQN), 256, 0, stream>>>(Tm, xT, bo, m_acc, v_acc,
                                                     gq, beta, out);
}